// Round 4
// baseline (2651.409 us; speedup 1.0000x reference)
//
#include <hip/hip_runtime.h>
#include <hip/hip_bf16.h>
#include <hip/hip_cooperative_groups.h>
#include <math.h>

// B=64 T=64 D=8 F=1024 H=1024 C=22 IN=4096; N rows = B*T = 4096.
// Decoder recurrence algebraically fused: for d>=1,
//   gates(d) = h(d-1) @ (Wih@Wdc + Whh)^T + (Wih@bdc + bih + bhh)   [K=1024]
// dec_scores batched into ONE M=32768 GEMM at the end.
//
// R1: XCD-chunked blockIdx swizzle: scores FETCH 265->54MB (kept, scores only).
// R2/R3 (reverted): counted-vmcnt ring regressed (occupancy + MfmaUtil down;
//     isolated pipeline on 128x128 2-phase structure is null-to-negative).
// R4: GEMM core reverted to the proven R0 body (BK=64, 2-barrier, 32KB LDS).
//     Decoder (dec0 + 7 steps, ~600us as 8 launches) fused into ONE
//     persistent cooperative kernel: c-state in REGISTERS across steps
//     (kills 224MB of cbuf fp32 RMW traffic), Wfus L2-resident across steps,
//     grid.sync() + __threadfence() between steps (agent-scope fence handles
//     cross-XCD L2 visibility). Fallback to the 8-launch path if cooperative
//     launch is rejected.
//
// ws layout (MB):
//  0   cbuf   fp32 [4096][1024]            16  (fallback path only)
//  16  wsH    bf16 [8][4096][1024]         64  (wsX overlays 16..48; ench overlays wsH[0])
//  80  feats  bf16 [4096][1024]             8
//  88  encH0  bf16 [4096][1024]             8
//  96  wsDecW bf16 [4096][2048] permuted   16
//  112 wsEncW bf16 [4096][2048] permuted   16
//  128 wsWf   bf16 [1024][4096]             8
//  136 wsWdc  bf16 [1024][1024]             2
//  138 wsWdcT bf16 [1024][1024] (Wdc^T)     2
//  140 wsWfus bf16 [4096][1024] permuted    8
//  148 wsWec  bf16 [22][1024]
//  149 wsB    fp32 [10262]  bf|decsum|encsum|bdc|bec
//  149+64K  wsBfus fp32 [4096]
//  149+96K  flag

typedef __attribute__((ext_vector_type(8))) short short8;
typedef __attribute__((ext_vector_type(4))) float f32x4;

#define BM 128
#define BN 128
#define BK 64

#define EPI_LIN    1
#define EPI_LSTM   2
#define EPI_SCORES 4
#define EPI_CLS    5

__device__ __forceinline__ float sigm(float x) { return 1.0f / (1.0f + __expf(-x)); }
__device__ __forceinline__ float tanh_f(float x) { return 1.0f - 2.0f / (__expf(2.0f * x) + 1.0f); }
__device__ __forceinline__ unsigned short f2bf(float f) {
  unsigned u = __float_as_uint(f);
  u += 0x7FFFu + ((u >> 16) & 1u);       // RNE
  return (unsigned short)(u >> 16);
}
__device__ __forceinline__ float bf2f(unsigned short h) {
  return __uint_as_float(((unsigned)h) << 16);
}

// fp32-vs-bf16 input detection: fp32 mantissa halves hit huge bf16 exponents.
__global__ void detect_kernel(const unsigned short* x, int* flag) {
  __shared__ int s;
  if (threadIdx.x == 0) s = 0;
  __syncthreads();
  int bad = 0;
  for (int i = threadIdx.x; i < 8192; i += 256) {
    unsigned e = (x[i] >> 7) & 0xFFu;
    if (e >= 0xC0u) bad = 1;
  }
  if (bad) atomicOr(&s, 1);
  __syncthreads();
  if (threadIdx.x == 0) *flag = s;   // 1 = fp32 inputs
}

__global__ void cvt_plain(const void* __restrict__ src, unsigned short* __restrict__ dst,
                          int n4, const int* __restrict__ flag) {
  int f = *flag;
  int i = blockIdx.x * blockDim.x + threadIdx.x;
  int st = gridDim.x * blockDim.x;
  if (f) {
    const float4* s = (const float4*)src;
    for (; i < n4; i += st) {
      float4 v = s[i];
      ushort4 o; o.x = f2bf(v.x); o.y = f2bf(v.y); o.z = f2bf(v.z); o.w = f2bf(v.w);
      ((ushort4*)dst)[i] = o;
    }
  } else {
    const ushort4* s = (const ushort4*)src;
    for (; i < n4; i += st) ((ushort4*)dst)[i] = s[i];
  }
}

// Gate-interleaved permuted concat [Wih | Whh] -> dst[4096][2048].
// packed row p -> orig gate row gate*1024+unit, gate=(p>>4)&3, unit=((p>>6)<<4)|(p&15)
__global__ void cvt_lstmw(const void* __restrict__ Wih, const void* __restrict__ Whh,
                          unsigned short* __restrict__ dst, const int* __restrict__ flag) {
  int f = *flag;
  int idx = blockIdx.x * blockDim.x + threadIdx.x;   // 4096*512 vec4 groups
  if (idx >= 4096 * 512) return;
  int p = idx >> 9;
  int k = (idx & 511) * 4;
  int gate = (p >> 4) & 3, unit = ((p >> 6) << 4) | (p & 15);
  size_t orig = (size_t)(gate * 1024 + unit);
  const void* sm; int kk;
  if (k < 1024) { sm = Wih; kk = k; } else { sm = Whh; kk = k - 1024; }
  size_t off = orig * 1024 + kk;
  ushort4 o;
  if (f) {
    float4 v = *(const float4*)((const float*)sm + off);
    o.x = f2bf(v.x); o.y = f2bf(v.y); o.z = f2bf(v.z); o.w = f2bf(v.w);
  } else {
    o = *(const ushort4*)((const unsigned short*)sm + off);
  }
  ((ushort4*)dst)[idx] = o;
}

// wsB: [0,1024)=bf  [1024,5120)=dbih+dbhh  [5120,9216)=ebih+ebhh
//      [9216,10240)=bdc  [10240,10262)=bec
__global__ void cvt_bias(const void* s0, const void* s1, const void* s2, const void* s3,
                         const void* s4, const void* s5, const void* s6,
                         float* __restrict__ dst, const int* __restrict__ flag) {
  int f = *flag;
  int i = blockIdx.x * blockDim.x + threadIdx.x;
  if (i >= 10262) return;
  auto ld = [f](const void* s, int j) -> float {
    return f ? ((const float*)s)[j] : bf2f(((const unsigned short*)s)[j]);
  };
  float v;
  if      (i < 1024)  v = ld(s0, i);
  else if (i < 5120)  v = ld(s1, i - 1024) + ld(s2, i - 1024);
  else if (i < 9216)  v = ld(s3, i - 5120) + ld(s4, i - 5120);
  else if (i < 10240) v = ld(s5, i - 9216);
  else                v = ld(s6, i - 10240);
  dst[i] = v;
}

// wsWdcT[n][k] = Wdc[k][n]  (bf16 out, dtype-adaptive in)
__global__ void trans_wdc(const void* __restrict__ src, unsigned short* __restrict__ dst,
                          const int* __restrict__ flag) {
  __shared__ float t[32][33];
  int f = *flag;
  int bx = blockIdx.x, by = blockIdx.y;
  int tx = threadIdx.x & 31, ty = threadIdx.x >> 5;
  for (int r = ty; r < 32; r += 8) {
    int sr = by * 32 + r, sc = bx * 32 + tx;
    t[r][tx] = f ? ((const float*)src)[(size_t)sr * 1024 + sc]
                 : bf2f(((const unsigned short*)src)[(size_t)sr * 1024 + sc]);
  }
  __syncthreads();
  for (int r = ty; r < 32; r += 8)
    dst[(size_t)(bx * 32 + r) * 1024 + by * 32 + tx] = f2bf(t[tx][r]);
}

// wsBfus[i] = decsum[i] + sum_j Wih[i][j]*bdc[j]   (orig gate-row index i)
__global__ void bias_dot(const void* __restrict__ Wih, const float* __restrict__ wsB,
                         float* __restrict__ out, const int* __restrict__ flag) {
  int i = blockIdx.x;
  int f = *flag;
  const float* bdc = wsB + 9216;
  float s = 0.f;
  for (int j = threadIdx.x; j < 1024; j += 256) {
    float wv = f ? ((const float*)Wih)[(size_t)i * 1024 + j]
                 : bf2f(((const unsigned short*)Wih)[(size_t)i * 1024 + j]);
    s += wv * bdc[j];
  }
  __shared__ float red[4];
  for (int o = 32; o > 0; o >>= 1) s += __shfl_down(s, o, 64);
  if ((threadIdx.x & 63) == 0) red[threadIdx.x >> 6] = s;
  __syncthreads();
  if (threadIdx.x == 0) out[i] = wsB[1024 + i] + red[0] + red[1] + red[2] + red[3];
}

// Persistent cooperative decoder: all 8 LSTM steps in one kernel.
// Block (bx,by) owns output tile rows [by*128,+128) x gate-rows [bx*128,+128)
// for ALL steps; per-thread c-state (16 values) lives in registers.
// Inner K-loop = the proven R0 GEMM core (BK=64, 2-barrier, chunk-XOR LDS
// swizzle, 0 bank conflicts). grid.sync() publishes h(d) between steps.
__global__ __launch_bounds__(256, 4) void dec_persist(
    const unsigned short* __restrict__ feats,
    const unsigned short* __restrict__ Wdec,   // [4096][2048] gate-permuted
    const unsigned short* __restrict__ Wfus,   // [4096][1024] gate-permuted
    const float* __restrict__ bias0,           // dec0 gate biases
    const float* __restrict__ biasf,           // fused gate biases
    unsigned short* __restrict__ wsH)          // [8][4096][1024]
{
  __shared__ unsigned short As[BM * BK];
  __shared__ unsigned short Bs[BN * BK];

  const int tid  = threadIdx.x;
  const int wv   = tid >> 6;
  const int lane = tid & 63;
  const int l15  = lane & 15;
  const int l7   = lane & 7;
  const int quad = lane >> 4;
  const int wm   = wv & 1;
  const int wn   = wv >> 1;
  const int row0 = blockIdx.y * BM;
  const int col0 = blockIdx.x * BN;

  const int cb = col0 + wn * 64;
  const int u  = ((cb >> 6) << 4) | l15;
  const float b0i = bias0[u], b0f = bias0[1024 + u], b0g = bias0[2048 + u], b0o = bias0[3072 + u];
  const float bfi = biasf[u], bff = biasf[1024 + u], bfg = biasf[2048 + u], bfo = biasf[3072 + u];

  const int rb = row0 + wm * 64 + quad * 4;

  float cst[4][4];
#pragma unroll
  for (int i = 0; i < 4; ++i)
#pragma unroll
    for (int r = 0; r < 4; ++r) cst[i][r] = 0.f;

  cooperative_groups::grid_group gg = cooperative_groups::this_grid();

  for (int d = 0; d < 8; ++d) {
    const unsigned short* A  = (d == 0) ? feats : wsH + (size_t)(d - 1) * 4194304;
    const unsigned short* Bm = (d == 0) ? Wdec : Wfus;
    const int ldB = (d == 0) ? 2048 : 1024;
    const float bi = (d == 0) ? b0i : bfi;
    const float bf_ = (d == 0) ? b0f : bff;
    const float bg = (d == 0) ? b0g : bfg;
    const float bo = (d == 0) ? b0o : bfo;

    f32x4 acc[4][4];
#pragma unroll
    for (int i = 0; i < 4; ++i)
#pragma unroll
      for (int j = 0; j < 4; ++j) acc[i][j] = (f32x4){0.f, 0.f, 0.f, 0.f};

    for (int k0 = 0; k0 < 1024; k0 += BK) {
      __syncthreads();
#pragma unroll
      for (int it = 0; it < 4; ++it) {
        int e  = (it * 256 + tid) * 8;
        int r  = e >> 6;
        int c8 = (e >> 3) & 7;
        int sc = ((c8 ^ (r & 7)) << 3);            // chunk-XOR swizzle
        const unsigned short* src = A + (size_t)(row0 + r) * 1024 + (k0 + sc);
        unsigned short* dst = As + (size_t)(it * 256 + wv * 64) * 8;
        __builtin_amdgcn_global_load_lds((const __attribute__((address_space(1))) void*)src,
                                         (__attribute__((address_space(3))) void*)dst, 16, 0, 0);
      }
#pragma unroll
      for (int it = 0; it < 4; ++it) {
        int e  = (it * 256 + tid) * 8;
        int r  = e >> 6;
        int c8 = (e >> 3) & 7;
        int sc = ((c8 ^ (r & 7)) << 3);
        const unsigned short* src = Bm + (size_t)(col0 + r) * ldB + (k0 + sc);
        unsigned short* dst = Bs + (size_t)(it * 256 + wv * 64) * 8;
        __builtin_amdgcn_global_load_lds((const __attribute__((address_space(1))) void*)src,
                                         (__attribute__((address_space(3))) void*)dst, 16, 0, 0);
      }
      __syncthreads();
#pragma unroll
      for (int kk = 0; kk < BK; kk += 32) {
        const int ko = kk >> 3;                    // 0 or 4
        short8 av[4], bv[4];
#pragma unroll
        for (int i = 0; i < 4; ++i) {
          int R = wm * 64 + i * 16 + l15;
          av[i] = *reinterpret_cast<const short8*>(&As[R * BK + (((quad + ko) ^ l7) << 3)]);
        }
#pragma unroll
        for (int j = 0; j < 4; ++j) {
          int R = wn * 64 + j * 16 + l15;
          bv[j] = *reinterpret_cast<const short8*>(&Bs[R * BK + (((quad + ko) ^ l7) << 3)]);
        }
#pragma unroll
        for (int i = 0; i < 4; ++i)
#pragma unroll
          for (int j = 0; j < 4; ++j)
            acc[i][j] = __builtin_amdgcn_mfma_f32_16x16x32_bf16(av[i], bv[j], acc[i][j], 0, 0, 0);
      }
    }

    unsigned short* hout = wsH + (size_t)d * 4194304;
#pragma unroll
    for (int mi = 0; mi < 4; ++mi)
#pragma unroll
      for (int r = 0; r < 4; ++r) {
        long long row = rb + mi * 16 + r;
        float iv = acc[mi][0][r] + bi;
        float fv = acc[mi][1][r] + bf_;
        float gv = acc[mi][2][r] + bg;
        float ov = acc[mi][3][r] + bo;
        float cn = sigm(fv) * cst[mi][r] + sigm(iv) * tanh_f(gv);
        cst[mi][r] = cn;
        hout[row * 1024 + u] = f2bf(sigm(ov) * tanh_f(cn));
      }

    if (d < 7) {
      __threadfence();          // agent-scope: L2 writeback/inv for cross-XCD
      gg.sync();
    }
  }
}

// NT GEMM C = A@B^T (bf16 in, fp32 acc), 128x128 tile, BK=64, 2-barrier
// single-buffer (R0 proven core), LDS chunk-XOR swizzle (0 bank conflicts).
// A split at BK-aligned splitKA. B rows clamped to nB-1.
// swzMode/chC: XCD-chunked blockIdx remap (scores GEMM only).
__global__ __launch_bounds__(256, 2) void gemm_fused(
    const unsigned short* __restrict__ A0, int ldA0,
    const unsigned short* __restrict__ A1, int ldA1, int splitKA,
    const unsigned short* __restrict__ B, int ldB, int K, int nB,
    const float* __restrict__ bias0,
    int mode, int do_relu, int czero,
    unsigned short* __restrict__ p1, long long ldc1,
    const unsigned short* __restrict__ addm, long long ldadd,
    void* __restrict__ dov, const int* __restrict__ of32flag,
    unsigned short* __restrict__ encH0,
    float* __restrict__ cbuf, int ncol,
    int swzMode, int chC)
{
  __shared__ unsigned short As[BM * BK];
  __shared__ unsigned short Bs[BN * BK];

  const int tid  = threadIdx.x;
  const int wv   = tid >> 6;
  const int lane = tid & 63;
  const int l15  = lane & 15;
  const int l7   = lane & 7;
  const int quad = lane >> 4;
  const int wm   = wv & 1;
  const int wn   = wv >> 1;

  int bx = blockIdx.x, by = blockIdx.y;
  if (swzMode) {
    const int nbx = gridDim.x, nby = gridDim.y;
    int w   = by * nbx + bx;
    int xcd = w & 7, loc = w >> 3;
    int ncc = nbx / chC;             // col-chunks
    int chR = (nby * ncc) >> 3;      // rows per chunk
    int cc  = xcd % ncc, cr = xcd / ncc;
    int r, c;
    if (swzMode == 1) { r = loc / chC; c = loc - r * chC; }
    else              { c = loc / chR; r = loc - c * chR; }
    by = cr * chR + r;
    bx = cc * chC + c;
  }
  const int row0 = by * BM;
  const int col0 = bx * BN;

  f32x4 acc[4][4];
#pragma unroll
  for (int i = 0; i < 4; ++i)
#pragma unroll
    for (int j = 0; j < 4; ++j) acc[i][j] = (f32x4){0.f, 0.f, 0.f, 0.f};

  for (int k0 = 0; k0 < K; k0 += BK) {
    __syncthreads();
    const unsigned short* Ab; int kA, ldA;
    if (k0 < splitKA) { Ab = A0; kA = k0;           ldA = ldA0; }
    else              { Ab = A1; kA = k0 - splitKA; ldA = ldA1; }

#pragma unroll
    for (int it = 0; it < 4; ++it) {
      int e  = (it * 256 + tid) * 8;
      int r  = e >> 6;
      int c8 = (e >> 3) & 7;
      int sc = ((c8 ^ (r & 7)) << 3);            // chunk-XOR swizzle
      const unsigned short* src = Ab + (size_t)(row0 + r) * ldA + (kA + sc);
      unsigned short* dst = As + (size_t)(it * 256 + wv * 64) * 8;
      __builtin_amdgcn_global_load_lds((const __attribute__((address_space(1))) void*)src,
                                       (__attribute__((address_space(3))) void*)dst, 16, 0, 0);
    }
#pragma unroll
    for (int it = 0; it < 4; ++it) {
      int e  = (it * 256 + tid) * 8;
      int r  = e >> 6;
      int c8 = (e >> 3) & 7;
      int sc = ((c8 ^ (r & 7)) << 3);
      int p  = col0 + r;
      int pr = (p < nB) ? p : (nB - 1);
      const unsigned short* src = B + (size_t)pr * ldB + (k0 + sc);
      unsigned short* dst = Bs + (size_t)(it * 256 + wv * 64) * 8;
      __builtin_amdgcn_global_load_lds((const __attribute__((address_space(1))) void*)src,
                                       (__attribute__((address_space(3))) void*)dst, 16, 0, 0);
    }
    __syncthreads();
#pragma unroll
    for (int kk = 0; kk < BK; kk += 32) {
      const int ko = kk >> 3;                    // 0 or 4
      short8 av[4], bv[4];
#pragma unroll
      for (int i = 0; i < 4; ++i) {
        int R = wm * 64 + i * 16 + l15;
        av[i] = *reinterpret_cast<const short8*>(&As[R * BK + (((quad + ko) ^ l7) << 3)]);
      }
#pragma unroll
      for (int j = 0; j < 4; ++j) {
        int R = wn * 64 + j * 16 + l15;
        bv[j] = *reinterpret_cast<const short8*>(&Bs[R * BK + (((quad + ko) ^ l7) << 3)]);
      }
#pragma unroll
      for (int i = 0; i < 4; ++i)
#pragma unroll
        for (int j = 0; j < 4; ++j)
          acc[i][j] = __builtin_amdgcn_mfma_f32_16x16x32_bf16(av[i], bv[j], acc[i][j], 0, 0, 0);
    }
  }

  // C/D layout (m89): col = lane&15, row = quad*4 + reg
  const int rb = row0 + wm * 64 + quad * 4;
  const int cb = col0 + wn * 64;

  if (mode == EPI_LIN) {
#pragma unroll
    for (int mi = 0; mi < 4; ++mi)
#pragma unroll
      for (int r = 0; r < 4; ++r) {
        long long row = rb + mi * 16 + r;
#pragma unroll
        for (int nj = 0; nj < 4; ++nj) {
          int col = cb + nj * 16 + l15;
          float v = acc[mi][nj][r] + (bias0 ? bias0[col] : 0.f);
          if (addm) v += bf2f(addm[row * ldadd + col]);
          if (do_relu) v = fmaxf(v, 0.f);
          p1[row * ldc1 + col] = f2bf(v);
        }
      }
  } else if (mode == EPI_LSTM) {
    const int u = ((cb >> 6) << 4) | l15;
    const float bi = bias0[u];
    const float bff= bias0[1024 + u];
    const float bg = bias0[2048 + u];
    const float bo = bias0[3072 + u];
#pragma unroll
    for (int mi = 0; mi < 4; ++mi)
#pragma unroll
      for (int r = 0; r < 4; ++r) {
        long long row = rb + mi * 16 + r;
        float iv = acc[mi][0][r] + bi;
        float fv = acc[mi][1][r] + bff;
        float gv = acc[mi][2][r] + bg;
        float ov = acc[mi][3][r] + bo;
        float co = (czero || !cbuf) ? 0.f : cbuf[row * 1024 + u];
        float cn = sigm(fv) * co + sigm(iv) * tanh_f(gv);
        if (cbuf) cbuf[row * 1024 + u] = cn;
        p1[row * ldc1 + u] = f2bf(sigm(ov) * tanh_f(cn));
      }
  } else if (mode == EPI_SCORES) {
    const int of32 = *of32flag;
#pragma unroll
    for (int mi = 0; mi < 4; ++mi)
#pragma unroll
      for (int r = 0; r < 4; ++r) {
        long long row = rb + mi * 16 + r;
        long long d = row >> 12, n = row & 4095;
#pragma unroll
        for (int nj = 0; nj < 4; ++nj) {
          int col = cb + nj * 16 + l15;
          float v = acc[mi][nj][r] + bias0[col];
          long long oi = 90112 + d * 1024 + n * 8192 + col;
          if (of32) ((float*)dov)[oi] = v;
          else      ((unsigned short*)dov)[oi] = f2bf(v);
          if (row >= 28672) encH0[n * 1024 + col] = f2bf(v * 0.125f);
        }
      }
  } else {  // EPI_CLS
    const int of32 = *of32flag;
#pragma unroll
    for (int mi = 0; mi < 4; ++mi)
#pragma unroll
      for (int r = 0; r < 4; ++r) {
        long long row = rb + mi * 16 + r;
#pragma unroll
        for (int nj = 0; nj < 4; ++nj) {
          int col = cb + nj * 16 + l15;
          if (col < ncol) {
            float v = acc[mi][nj][r] + bias0[col];
            long long oi = row * ncol + col;
            if (of32) ((float*)dov)[oi] = v;
            else      ((unsigned short*)dov)[oi] = f2bf(v);
          }
        }
      }
  }
}

extern "C" void kernel_launch(void* const* d_in, const int* in_sizes, int n_in,
                              void* d_out, int out_size, void* d_ws, size_t ws_size,
                              hipStream_t stream) {
  const void* x    = d_in[0];
  const void* Wf   = d_in[1];
  const void* bf_  = d_in[2];
  const void* dWih = d_in[3];
  const void* dWhh = d_in[4];
  const void* dbih = d_in[5];
  const void* dbhh = d_in[6];
  const void* Wdc  = d_in[7];
  const void* bdc  = d_in[8];
  const void* eWih = d_in[9];
  const void* eWhh = d_in[10];
  const void* ebih = d_in[11];
  const void* ebhh = d_in[12];
  const void* Wec  = d_in[13];
  const void* bec  = d_in[14];

  char* w = (char*)d_ws;
  const size_t MB = 1u << 20;
  float*          cbuf   = (float*)(w);
  unsigned short* wsH    = (unsigned short*)(w + 16 * MB);   // [8][4096][1024]
  unsigned short* wsX    = (unsigned short*)(w + 16 * MB);   // overlays wsH[0..3] (dead after L1)
  unsigned short* ench   = (unsigned short*)(w + 16 * MB);   // overlays wsH[0] (after scores GEMM)
  unsigned short* feats  = (unsigned short*)(w + 80 * MB);
  unsigned short* encH0  = (unsigned short*)(w + 88 * MB);
  unsigned short* wsDecW = (unsigned short*)(w + 96 * MB);
  unsigned short* wsEncW = (unsigned short*)(w + 112 * MB);
  unsigned short* wsWf   = (unsigned short*)(w + 128 * MB);
  unsigned short* wsWdc  = (unsigned short*)(w + 136 * MB);
  unsigned short* wsWdcT = (unsigned short*)(w + 138 * MB);
  unsigned short* wsWfus = (unsigned short*)(w + 140 * MB);
  unsigned short* wsWec  = (unsigned short*)(w + 148 * MB);
  float*          wsB    = (float*)(w + 149 * MB);
  float*          wsBfus = (float*)(w + 149 * MB + 64 * 1024);
  int*            flag   = (int*)(w + 149 * MB + 96 * 1024);

  const int BIG = 1 << 30;

  detect_kernel<<<1, 256, 0, stream>>>((const unsigned short*)x, flag);

  cvt_plain<<<4096, 256, 0, stream>>>(x,   wsX,  16777216 / 4, flag);
  cvt_plain<<<2048, 256, 0, stream>>>(Wf,  wsWf,  4194304 / 4, flag);
  cvt_plain<<<1024, 256, 0, stream>>>(Wdc, wsWdc, 1048576 / 4, flag);
  cvt_plain<<<22,   256, 0, stream>>>(Wec, wsWec,   22528 / 4, flag);
  cvt_lstmw<<<8192, 256, 0, stream>>>(dWih, dWhh, wsDecW, flag);
  cvt_lstmw<<<8192, 256, 0, stream>>>(eWih, eWhh, wsEncW, flag);
  cvt_bias<<<41, 256, 0, stream>>>(bf_, dbih, dbhh, ebih, ebhh, bdc, bec, wsB, flag);
  trans_wdc<<<dim3(32, 32), 256, 0, stream>>>(Wdc, wsWdcT, flag);
  bias_dot<<<4096, 256, 0, stream>>>(dWih, wsB, wsBfus, flag);

  // Wfus = permWih @ Wdc + permWhh  (rows stay gate-permuted)
  gemm_fused<<<dim3(8, 32), 256, 0, stream>>>(
      wsDecW, 2048, nullptr, 0, BIG, wsWdcT, 1024, 1024, 1024,
      nullptr, EPI_LIN, 0, 0, wsWfus, 1024, wsDecW + 1024, 2048,
      nullptr, flag, nullptr, nullptr, 1024, 0, 1);

  // L1: feats = relu(x @ Wf^T + bf)
  gemm_fused<<<dim3(8, 32), 256, 0, stream>>>(
      wsX, 4096, nullptr, 0, BIG, wsWf, 4096, 4096, 1024,
      wsB, EPI_LIN, 1, 0, feats, 1024, nullptr, 0,
      nullptr, flag, nullptr, nullptr, 1024, 0, 1);

  // decoder steps 0..7 in ONE persistent cooperative kernel, c in registers.
  {
    const unsigned short* a_feats = feats;
    const unsigned short* a_wdec  = wsDecW;
    const unsigned short* a_wfus  = wsWfus;
    const float*          a_b0    = wsB + 1024;
    const float*          a_bf    = wsBfus;
    unsigned short*       a_wsH   = wsH;
    void* ka[6] = { &a_feats, &a_wdec, &a_wfus, &a_b0, &a_bf, &a_wsH };
    hipError_t ce = hipLaunchCooperativeKernel(
        (const void*)dec_persist, dim3(32, 32), dim3(256), ka, 0, stream);
    if (ce != hipSuccess) {
      // fallback: original 8-launch path through gemm_fused (cbuf-based)
      gemm_fused<<<dim3(32, 32), 256, 0, stream>>>(
          feats, 1024, nullptr, 0, BIG, wsDecW, 2048, 1024, 4096,
          wsB + 1024, EPI_LSTM, 0, 1, wsH, 1024, nullptr, 0,
          nullptr, flag, nullptr, cbuf, 1024, 0, 1);
      for (int d = 1; d < 8; ++d) {
        gemm_fused<<<dim3(32, 32), 256, 0, stream>>>(
            wsH + (size_t)(d - 1) * 4194304, 1024, nullptr, 0, BIG, wsWfus, 1024, 1024, 4096,
            wsBfus, EPI_LSTM, 0, 0, wsH + (size_t)d * 4194304, 1024, nullptr, 0,
            nullptr, flag, nullptr, cbuf, 1024, 0, 1);
      }
    }
  }

  // dec_scores (all 8 steps) = H[32768][1024] @ Wdc^T + bdc; tail rows also
  // write enc_h0 = out(7)/8
  // grid 8x256: full-width chunk 32r x 8c, row-major walk -> A fetched once
  gemm_fused<<<dim3(8, 256), 256, 0, stream>>>(
      wsH, 1024, nullptr, 0, BIG, wsWdc, 1024, 1024, 1024,
      wsB + 9216, EPI_SCORES, 0, 0, nullptr, 0, nullptr, 0,
      d_out, flag, encH0, nullptr, 1024, 1, 8);

  // encoder: one LSTM step on [feats | enc_h0], c0=0; h -> ench (no c write)
  gemm_fused<<<dim3(32, 32), 256, 0, stream>>>(
      feats, 1024, encH0, 1024, 1024, wsEncW, 2048, 2048, 4096,
      wsB + 5120, EPI_LSTM, 0, 1, ench, 1024, nullptr, 0,
      nullptr, flag, nullptr, nullptr, 1024, 0, 1);

  // classifier: enc_scores = ench @ Wec^T + bec (N=22)
  gemm_fused<<<dim3(1, 32), 256, 0, stream>>>(
      ench, 1024, nullptr, 0, BIG, wsWec, 1024, 1024, 22,
      wsB + 10240, EPI_CLS, 0, 0, nullptr, 0, nullptr, 0,
      d_out, flag, nullptr, nullptr, 22, 0, 1);
}

// Round 5
// 920.342 us; speedup vs baseline: 2.8809x; 2.8809x over previous
//
#include <hip/hip_runtime.h>
#include <hip/hip_bf16.h>
#include <math.h>

// B=64 T=64 D=8 F=1024 H=1024 C=22 IN=4096; N rows = B*T = 4096.
// Decoder recurrence algebraically fused: for d>=1,
//   gates(d) = h(d-1) @ (Wih@Wdc + Whh)^T + (Wih@bdc + bih + bhh)   [K=1024]
// dec_scores batched into ONE M=32768 GEMM at the end.
//
// R1: XCD-chunked blockIdx swizzle: scores FETCH 265->54MB (kept).
// R2/R3 (reverted): counted-vmcnt ring regressed (occupancy+MfmaUtil down).
// R4 (reverted): cooperative persistent decoder: grid.sync() ~300us/sync on
//     8 non-coherent XCDs (7 syncs = 2.1ms, MfmaUtil 5%); __threadfence()
//     L2-invalidate pushed FETCH to 559MB. Cooperative is a dead end here;
//     kernel-launch boundaries (~10us) are the cheap device-wide barrier.
// R5: restore proven config: R0 GEMM core everywhere + scores swizzle +
//     dec/enc 16rx8c chunk (R3-measured FETCH 65.7MB) + Wfus 4rx8c chunk
//     (WS 3MB < L2). L1 default mapping (chunked WS 12MB > L2 = thrash).
//     czero bitfield: skip dead cbuf writes on dec step 7 and encoder.
//
// ws layout (MB):
//  0   cbuf   fp32 [4096][1024]            16
//  16  wsH    bf16 [8][4096][1024]         64   (wsX overlays 16..48; ench overlays wsH[0])
//  80  feats  bf16 [4096][1024]             8
//  88  encH0  bf16 [4096][1024]             8
//  96  wsDecW bf16 [4096][2048] permuted   16
//  112 wsEncW bf16 [4096][2048] permuted   16
//  128 wsWf   bf16 [1024][4096]             8
//  136 wsWdc  bf16 [1024][1024]             2
//  138 wsWdcT bf16 [1024][1024] (Wdc^T)     2
//  140 wsWfus bf16 [4096][1024] permuted    8
//  148 wsWec  bf16 [22][1024]
//  149 wsB    fp32 [10262]  bf|decsum|encsum|bdc|bec
//  149+64K  wsBfus fp32 [4096]
//  149+96K  flag

typedef __attribute__((ext_vector_type(8))) short short8;
typedef __attribute__((ext_vector_type(4))) float f32x4;

#define BM 128
#define BN 128
#define BK 64

#define EPI_LIN    1
#define EPI_LSTM   2
#define EPI_SCORES 4
#define EPI_CLS    5

__device__ __forceinline__ float sigm(float x) { return 1.0f / (1.0f + __expf(-x)); }
__device__ __forceinline__ float tanh_f(float x) { return 1.0f - 2.0f / (__expf(2.0f * x) + 1.0f); }
__device__ __forceinline__ unsigned short f2bf(float f) {
  unsigned u = __float_as_uint(f);
  u += 0x7FFFu + ((u >> 16) & 1u);       // RNE
  return (unsigned short)(u >> 16);
}
__device__ __forceinline__ float bf2f(unsigned short h) {
  return __uint_as_float(((unsigned)h) << 16);
}

// fp32-vs-bf16 input detection: fp32 mantissa halves hit huge bf16 exponents.
__global__ void detect_kernel(const unsigned short* x, int* flag) {
  __shared__ int s;
  if (threadIdx.x == 0) s = 0;
  __syncthreads();
  int bad = 0;
  for (int i = threadIdx.x; i < 8192; i += 256) {
    unsigned e = (x[i] >> 7) & 0xFFu;
    if (e >= 0xC0u) bad = 1;
  }
  if (bad) atomicOr(&s, 1);
  __syncthreads();
  if (threadIdx.x == 0) *flag = s;   // 1 = fp32 inputs
}

__global__ void cvt_plain(const void* __restrict__ src, unsigned short* __restrict__ dst,
                          int n4, const int* __restrict__ flag) {
  int f = *flag;
  int i = blockIdx.x * blockDim.x + threadIdx.x;
  int st = gridDim.x * blockDim.x;
  if (f) {
    const float4* s = (const float4*)src;
    for (; i < n4; i += st) {
      float4 v = s[i];
      ushort4 o; o.x = f2bf(v.x); o.y = f2bf(v.y); o.z = f2bf(v.z); o.w = f2bf(v.w);
      ((ushort4*)dst)[i] = o;
    }
  } else {
    const ushort4* s = (const ushort4*)src;
    for (; i < n4; i += st) ((ushort4*)dst)[i] = s[i];
  }
}

// Gate-interleaved permuted concat [Wih | Whh] -> dst[4096][2048].
// packed row p -> orig gate row gate*1024+unit, gate=(p>>4)&3, unit=((p>>6)<<4)|(p&15)
__global__ void cvt_lstmw(const void* __restrict__ Wih, const void* __restrict__ Whh,
                          unsigned short* __restrict__ dst, const int* __restrict__ flag) {
  int f = *flag;
  int idx = blockIdx.x * blockDim.x + threadIdx.x;   // 4096*512 vec4 groups
  if (idx >= 4096 * 512) return;
  int p = idx >> 9;
  int k = (idx & 511) * 4;
  int gate = (p >> 4) & 3, unit = ((p >> 6) << 4) | (p & 15);
  size_t orig = (size_t)(gate * 1024 + unit);
  const void* sm; int kk;
  if (k < 1024) { sm = Wih; kk = k; } else { sm = Whh; kk = k - 1024; }
  size_t off = orig * 1024 + kk;
  ushort4 o;
  if (f) {
    float4 v = *(const float4*)((const float*)sm + off);
    o.x = f2bf(v.x); o.y = f2bf(v.y); o.z = f2bf(v.z); o.w = f2bf(v.w);
  } else {
    o = *(const ushort4*)((const unsigned short*)sm + off);
  }
  ((ushort4*)dst)[idx] = o;
}

// wsB: [0,1024)=bf  [1024,5120)=dbih+dbhh  [5120,9216)=ebih+ebhh
//      [9216,10240)=bdc  [10240,10262)=bec
__global__ void cvt_bias(const void* s0, const void* s1, const void* s2, const void* s3,
                         const void* s4, const void* s5, const void* s6,
                         float* __restrict__ dst, const int* __restrict__ flag) {
  int f = *flag;
  int i = blockIdx.x * blockDim.x + threadIdx.x;
  if (i >= 10262) return;
  auto ld = [f](const void* s, int j) -> float {
    return f ? ((const float*)s)[j] : bf2f(((const unsigned short*)s)[j]);
  };
  float v;
  if      (i < 1024)  v = ld(s0, i);
  else if (i < 5120)  v = ld(s1, i - 1024) + ld(s2, i - 1024);
  else if (i < 9216)  v = ld(s3, i - 5120) + ld(s4, i - 5120);
  else if (i < 10240) v = ld(s5, i - 9216);
  else                v = ld(s6, i - 10240);
  dst[i] = v;
}

// wsWdcT[n][k] = Wdc[k][n]  (bf16 out, dtype-adaptive in)
__global__ void trans_wdc(const void* __restrict__ src, unsigned short* __restrict__ dst,
                          const int* __restrict__ flag) {
  __shared__ float t[32][33];
  int f = *flag;
  int bx = blockIdx.x, by = blockIdx.y;
  int tx = threadIdx.x & 31, ty = threadIdx.x >> 5;
  for (int r = ty; r < 32; r += 8) {
    int sr = by * 32 + r, sc = bx * 32 + tx;
    t[r][tx] = f ? ((const float*)src)[(size_t)sr * 1024 + sc]
                 : bf2f(((const unsigned short*)src)[(size_t)sr * 1024 + sc]);
  }
  __syncthreads();
  for (int r = ty; r < 32; r += 8)
    dst[(size_t)(bx * 32 + r) * 1024 + by * 32 + tx] = f2bf(t[tx][r]);
}

// wsBfus[i] = decsum[i] + sum_j Wih[i][j]*bdc[j]   (orig gate-row index i)
__global__ void bias_dot(const void* __restrict__ Wih, const float* __restrict__ wsB,
                         float* __restrict__ out, const int* __restrict__ flag) {
  int i = blockIdx.x;
  int f = *flag;
  const float* bdc = wsB + 9216;
  float s = 0.f;
  for (int j = threadIdx.x; j < 1024; j += 256) {
    float wv = f ? ((const float*)Wih)[(size_t)i * 1024 + j]
                 : bf2f(((const unsigned short*)Wih)[(size_t)i * 1024 + j]);
    s += wv * bdc[j];
  }
  __shared__ float red[4];
  for (int o = 32; o > 0; o >>= 1) s += __shfl_down(s, o, 64);
  if ((threadIdx.x & 63) == 0) red[threadIdx.x >> 6] = s;
  __syncthreads();
  if (threadIdx.x == 0) out[i] = wsB[1024 + i] + red[0] + red[1] + red[2] + red[3];
}

// NT GEMM C = A@B^T (bf16 in, fp32 acc), 128x128 tile, BK=64, 2-barrier
// single-buffer (R0 proven core), LDS chunk-XOR swizzle (0 bank conflicts).
// A split at BK-aligned splitKA. B rows clamped to nB-1.
// czero bits: bit0 = c-in is zero (skip read), bit1 = skip c write.
// swzMode/chC: XCD-chunked blockIdx remap.
__global__ __launch_bounds__(256, 2) void gemm_fused(
    const unsigned short* __restrict__ A0, int ldA0,
    const unsigned short* __restrict__ A1, int ldA1, int splitKA,
    const unsigned short* __restrict__ B, int ldB, int K, int nB,
    const float* __restrict__ bias0,
    int mode, int do_relu, int czero,
    unsigned short* __restrict__ p1, long long ldc1,
    const unsigned short* __restrict__ addm, long long ldadd,
    void* __restrict__ dov, const int* __restrict__ of32flag,
    unsigned short* __restrict__ encH0,
    float* __restrict__ cbuf, int ncol,
    int swzMode, int chC)
{
  __shared__ unsigned short As[BM * BK];
  __shared__ unsigned short Bs[BN * BK];

  const int tid  = threadIdx.x;
  const int wv   = tid >> 6;
  const int lane = tid & 63;
  const int l15  = lane & 15;
  const int l7   = lane & 7;
  const int quad = lane >> 4;
  const int wm   = wv & 1;
  const int wn   = wv >> 1;

  int bx = blockIdx.x, by = blockIdx.y;
  if (swzMode) {
    const int nbx = gridDim.x, nby = gridDim.y;
    int w   = by * nbx + bx;
    int xcd = w & 7, loc = w >> 3;
    int ncc = nbx / chC;             // col-chunks
    int chR = (nby * ncc) >> 3;      // rows per chunk
    int cc  = xcd % ncc, cr = xcd / ncc;
    int r, c;
    if (swzMode == 1) { r = loc / chC; c = loc - r * chC; }
    else              { c = loc / chR; r = loc - c * chR; }
    by = cr * chR + r;
    bx = cc * chC + c;
  }
  const int row0 = by * BM;
  const int col0 = bx * BN;

  f32x4 acc[4][4];
#pragma unroll
  for (int i = 0; i < 4; ++i)
#pragma unroll
    for (int j = 0; j < 4; ++j) acc[i][j] = (f32x4){0.f, 0.f, 0.f, 0.f};

  for (int k0 = 0; k0 < K; k0 += BK) {
    __syncthreads();
    const unsigned short* Ab; int kA, ldA;
    if (k0 < splitKA) { Ab = A0; kA = k0;           ldA = ldA0; }
    else              { Ab = A1; kA = k0 - splitKA; ldA = ldA1; }

#pragma unroll
    for (int it = 0; it < 4; ++it) {
      int e  = (it * 256 + tid) * 8;
      int r  = e >> 6;
      int c8 = (e >> 3) & 7;
      int sc = ((c8 ^ (r & 7)) << 3);            // chunk-XOR swizzle
      const unsigned short* src = Ab + (size_t)(row0 + r) * ldA + (kA + sc);
      unsigned short* dst = As + (size_t)(it * 256 + wv * 64) * 8;
      __builtin_amdgcn_global_load_lds((const __attribute__((address_space(1))) void*)src,
                                       (__attribute__((address_space(3))) void*)dst, 16, 0, 0);
    }
#pragma unroll
    for (int it = 0; it < 4; ++it) {
      int e  = (it * 256 + tid) * 8;
      int r  = e >> 6;
      int c8 = (e >> 3) & 7;
      int sc = ((c8 ^ (r & 7)) << 3);
      int p  = col0 + r;
      int pr = (p < nB) ? p : (nB - 1);
      const unsigned short* src = B + (size_t)pr * ldB + (k0 + sc);
      unsigned short* dst = Bs + (size_t)(it * 256 + wv * 64) * 8;
      __builtin_amdgcn_global_load_lds((const __attribute__((address_space(1))) void*)src,
                                       (__attribute__((address_space(3))) void*)dst, 16, 0, 0);
    }
    __syncthreads();
#pragma unroll
    for (int kk = 0; kk < BK; kk += 32) {
      const int ko = kk >> 3;                    // 0 or 4
      short8 av[4], bv[4];
#pragma unroll
      for (int i = 0; i < 4; ++i) {
        int R = wm * 64 + i * 16 + l15;
        av[i] = *reinterpret_cast<const short8*>(&As[R * BK + (((quad + ko) ^ l7) << 3)]);
      }
#pragma unroll
      for (int j = 0; j < 4; ++j) {
        int R = wn * 64 + j * 16 + l15;
        bv[j] = *reinterpret_cast<const short8*>(&Bs[R * BK + (((quad + ko) ^ l7) << 3)]);
      }
#pragma unroll
      for (int i = 0; i < 4; ++i)
#pragma unroll
        for (int j = 0; j < 4; ++j)
          acc[i][j] = __builtin_amdgcn_mfma_f32_16x16x32_bf16(av[i], bv[j], acc[i][j], 0, 0, 0);
    }
  }

  // C/D layout (m89): col = lane&15, row = quad*4 + reg
  const int rb = row0 + wm * 64 + quad * 4;
  const int cb = col0 + wn * 64;

  if (mode == EPI_LIN) {
#pragma unroll
    for (int mi = 0; mi < 4; ++mi)
#pragma unroll
      for (int r = 0; r < 4; ++r) {
        long long row = rb + mi * 16 + r;
#pragma unroll
        for (int nj = 0; nj < 4; ++nj) {
          int col = cb + nj * 16 + l15;
          float v = acc[mi][nj][r] + (bias0 ? bias0[col] : 0.f);
          if (addm) v += bf2f(addm[row * ldadd + col]);
          if (do_relu) v = fmaxf(v, 0.f);
          p1[row * ldc1 + col] = f2bf(v);
        }
      }
  } else if (mode == EPI_LSTM) {
    const int u = ((cb >> 6) << 4) | l15;
    const float bi = bias0[u];
    const float bff= bias0[1024 + u];
    const float bg = bias0[2048 + u];
    const float bo = bias0[3072 + u];
#pragma unroll
    for (int mi = 0; mi < 4; ++mi)
#pragma unroll
      for (int r = 0; r < 4; ++r) {
        long long row = rb + mi * 16 + r;
        float iv = acc[mi][0][r] + bi;
        float fv = acc[mi][1][r] + bff;
        float gv = acc[mi][2][r] + bg;
        float ov = acc[mi][3][r] + bo;
        float co = ((czero & 1) || !cbuf) ? 0.f : cbuf[row * 1024 + u];
        float cn = sigm(fv) * co + sigm(iv) * tanh_f(gv);
        if (cbuf && !(czero & 2)) cbuf[row * 1024 + u] = cn;
        p1[row * ldc1 + u] = f2bf(sigm(ov) * tanh_f(cn));
      }
  } else if (mode == EPI_SCORES) {
    const int of32 = *of32flag;
#pragma unroll
    for (int mi = 0; mi < 4; ++mi)
#pragma unroll
      for (int r = 0; r < 4; ++r) {
        long long row = rb + mi * 16 + r;
        long long d = row >> 12, n = row & 4095;
#pragma unroll
        for (int nj = 0; nj < 4; ++nj) {
          int col = cb + nj * 16 + l15;
          float v = acc[mi][nj][r] + bias0[col];
          long long oi = 90112 + d * 1024 + n * 8192 + col;
          if (of32) ((float*)dov)[oi] = v;
          else      ((unsigned short*)dov)[oi] = f2bf(v);
          if (row >= 28672) encH0[n * 1024 + col] = f2bf(v * 0.125f);
        }
      }
  } else {  // EPI_CLS
    const int of32 = *of32flag;
#pragma unroll
    for (int mi = 0; mi < 4; ++mi)
#pragma unroll
      for (int r = 0; r < 4; ++r) {
        long long row = rb + mi * 16 + r;
#pragma unroll
        for (int nj = 0; nj < 4; ++nj) {
          int col = cb + nj * 16 + l15;
          if (col < ncol) {
            float v = acc[mi][nj][r] + bias0[col];
            long long oi = row * ncol + col;
            if (of32) ((float*)dov)[oi] = v;
            else      ((unsigned short*)dov)[oi] = f2bf(v);
          }
        }
      }
  }
}

extern "C" void kernel_launch(void* const* d_in, const int* in_sizes, int n_in,
                              void* d_out, int out_size, void* d_ws, size_t ws_size,
                              hipStream_t stream) {
  const void* x    = d_in[0];
  const void* Wf   = d_in[1];
  const void* bf_  = d_in[2];
  const void* dWih = d_in[3];
  const void* dWhh = d_in[4];
  const void* dbih = d_in[5];
  const void* dbhh = d_in[6];
  const void* Wdc  = d_in[7];
  const void* bdc  = d_in[8];
  const void* eWih = d_in[9];
  const void* eWhh = d_in[10];
  const void* ebih = d_in[11];
  const void* ebhh = d_in[12];
  const void* Wec  = d_in[13];
  const void* bec  = d_in[14];

  char* w = (char*)d_ws;
  const size_t MB = 1u << 20;
  float*          cbuf   = (float*)(w);
  unsigned short* wsH    = (unsigned short*)(w + 16 * MB);   // [8][4096][1024]
  unsigned short* wsX    = (unsigned short*)(w + 16 * MB);   // overlays wsH[0..3] (dead after L1)
  unsigned short* ench   = (unsigned short*)(w + 16 * MB);   // overlays wsH[0] (after scores GEMM)
  unsigned short* feats  = (unsigned short*)(w + 80 * MB);
  unsigned short* encH0  = (unsigned short*)(w + 88 * MB);
  unsigned short* wsDecW = (unsigned short*)(w + 96 * MB);
  unsigned short* wsEncW = (unsigned short*)(w + 112 * MB);
  unsigned short* wsWf   = (unsigned short*)(w + 128 * MB);
  unsigned short* wsWdc  = (unsigned short*)(w + 136 * MB);
  unsigned short* wsWdcT = (unsigned short*)(w + 138 * MB);
  unsigned short* wsWfus = (unsigned short*)(w + 140 * MB);
  unsigned short* wsWec  = (unsigned short*)(w + 148 * MB);
  float*          wsB    = (float*)(w + 149 * MB);
  float*          wsBfus = (float*)(w + 149 * MB + 64 * 1024);
  int*            flag   = (int*)(w + 149 * MB + 96 * 1024);

  const int BIG = 1 << 30;

  detect_kernel<<<1, 256, 0, stream>>>((const unsigned short*)x, flag);

  cvt_plain<<<4096, 256, 0, stream>>>(x,   wsX,  16777216 / 4, flag);
  cvt_plain<<<2048, 256, 0, stream>>>(Wf,  wsWf,  4194304 / 4, flag);
  cvt_plain<<<1024, 256, 0, stream>>>(Wdc, wsWdc, 1048576 / 4, flag);
  cvt_plain<<<22,   256, 0, stream>>>(Wec, wsWec,   22528 / 4, flag);
  cvt_lstmw<<<8192, 256, 0, stream>>>(dWih, dWhh, wsDecW, flag);
  cvt_lstmw<<<8192, 256, 0, stream>>>(eWih, eWhh, wsEncW, flag);
  cvt_bias<<<41, 256, 0, stream>>>(bf_, dbih, dbhh, ebih, ebhh, bdc, bec, wsB, flag);
  trans_wdc<<<dim3(32, 32), 256, 0, stream>>>(Wdc, wsWdcT, flag);
  bias_dot<<<4096, 256, 0, stream>>>(dWih, wsB, wsBfus, flag);

  // Wfus = permWih @ Wdc + permWhh  (rows stay gate-permuted)
  // grid 8x32: 4r x 8c chunk, col-major walk (WS 3MB < 4MB L2)
  gemm_fused<<<dim3(8, 32), 256, 0, stream>>>(
      wsDecW, 2048, nullptr, 0, BIG, wsWdcT, 1024, 1024, 1024,
      nullptr, EPI_LIN, 0, 0, wsWfus, 1024, wsDecW + 1024, 2048,
      nullptr, flag, nullptr, nullptr, 1024, 2, 8);

  // L1: feats = relu(x @ Wf^T + bf)
  // default mapping (chunked variant: WS 12MB > 4MB L2 -> thrash, R1 lesson)
  gemm_fused<<<dim3(8, 32), 256, 0, stream>>>(
      wsX, 4096, nullptr, 0, BIG, wsWf, 4096, 4096, 1024,
      wsB, EPI_LIN, 1, 0, feats, 1024, nullptr, 0,
      nullptr, flag, nullptr, nullptr, 1024, 0, 1);

  // decoder step 0: gates = feats @ Wih^T + (bih+bhh); h0=c0=0
  // grid 32x32: 16r x 8c chunks, row-major walk (R3-measured FETCH 65.7MB)
  gemm_fused<<<dim3(32, 32), 256, 0, stream>>>(
      feats, 1024, nullptr, 0, BIG, wsDecW, 2048, 1024, 4096,
      wsB + 1024, EPI_LSTM, 0, 1, wsH, 1024, nullptr, 0,
      nullptr, flag, nullptr, cbuf, 1024, 1, 8);

  // decoder steps 1..7: gates = h(d-1) @ Wfus^T + bfus
  // step 7 skips the dead cbuf write (czero bit1)
  for (int d = 1; d < 8; ++d) {
    gemm_fused<<<dim3(32, 32), 256, 0, stream>>>(
        wsH + (size_t)(d - 1) * 4194304, 1024, nullptr, 0, BIG, wsWfus, 1024, 1024, 4096,
        wsBfus, EPI_LSTM, 0, (d == 7) ? 2 : 0, wsH + (size_t)d * 4194304, 1024, nullptr, 0,
        nullptr, flag, nullptr, cbuf, 1024, 1, 8);
  }

  // dec_scores (all 8 steps) = H[32768][1024] @ Wdc^T + bdc; tail rows also
  // write enc_h0 = out(7)/8
  // grid 8x256: full-width chunk 32r x 8c, row-major walk -> A fetched once
  gemm_fused<<<dim3(8, 256), 256, 0, stream>>>(
      wsH, 1024, nullptr, 0, BIG, wsWdc, 1024, 1024, 1024,
      wsB + 9216, EPI_SCORES, 0, 0, nullptr, 0, nullptr, 0,
      d_out, flag, encH0, nullptr, 1024, 1, 8);

  // encoder: one LSTM step on [feats | enc_h0], c0=0; h -> ench; no c write
  gemm_fused<<<dim3(32, 32), 256, 0, stream>>>(
      feats, 1024, encH0, 1024, 1024, wsEncW, 2048, 2048, 4096,
      wsB + 5120, EPI_LSTM, 0, 3, ench, 1024, nullptr, 0,
      nullptr, flag, nullptr, nullptr, 1024, 1, 8);

  // classifier: enc_scores = ench @ Wec^T + bec (N=22)
  gemm_fused<<<dim3(1, 32), 256, 0, stream>>>(
      ench, 1024, nullptr, 0, BIG, wsWec, 1024, 1024, 22,
      wsB + 10240, EPI_CLS, 0, 0, nullptr, 0, nullptr, 0,
      d_out, flag, nullptr, nullptr, 22, 0, 1);
}